// Round 9
// baseline (354.518 us; speedup 1.0000x reference)
//
#include <hip/hip_runtime.h>
#include <math.h>

#define BN 4096
#define N_PER_B 64
#define NE 16384
#define NSEL 65536
#define NET 5
#define PD 64
#define H1STR 260   // pair LDS stride (shorts)
#define FSTR 264    // mega LDS stride
#define PTILES 4

typedef float f32x4 __attribute__((ext_vector_type(4)));
typedef float f32x16 __attribute__((ext_vector_type(16)));
typedef short short8 __attribute__((ext_vector_type(8)));
typedef short short4v __attribute__((ext_vector_type(4)));

__device__ __forceinline__ unsigned short f2bf(float f) {
    unsigned int u = __builtin_bit_cast(unsigned int, f);
    u += 0x7fff + ((u >> 16) & 1);          // RNE
    return (unsigned short)(u >> 16);
}
__device__ __forceinline__ float bf_lo(unsigned int u) {
    return __builtin_bit_cast(float, u << 16);
}
__device__ __forceinline__ float bf_hi(unsigned int u) {
    return __builtin_bit_cast(float, u & 0xffff0000u);
}
__device__ __forceinline__ unsigned int pack2(float a, float b) {
    return (unsigned)f2bf(a) | ((unsigned)f2bf(b) << 16);
}
__device__ __forceinline__ short8 ld_frag(const unsigned short* p) {
    const short4v lo = *(const short4v*)(p);
    const short4v hi = *(const short4v*)(p + 4);
    return __builtin_shufflevector(lo, hi, 0, 1, 2, 3, 4, 5, 6, 7);
}
__device__ __forceinline__ unsigned int addrelu2(unsigned int a, unsigned int b, unsigned int c) {
    const float lo = fmaxf(bf_lo(a) + bf_lo(b) + bf_lo(c), 0.f);
    const float hi = fmaxf(bf_hi(a) + bf_hi(b) + bf_hi(c), 0.f);
    return pack2(lo, hi);
}

// Grid barrier: all 256 blocks co-resident (1 block/CU). Release fence (wbl2)
// before arrive; acquire fence (inv L1/L2) after the spin completes.
__device__ __forceinline__ void grid_barrier(int* cnt, int target) {
    __syncthreads();
    if (threadIdx.x == 0) {
        __threadfence();
        __hip_atomic_fetch_add(cnt, 1, __ATOMIC_RELAXED, __HIP_MEMORY_SCOPE_AGENT);
        while (__hip_atomic_load(cnt, __ATOMIC_RELAXED, __HIP_MEMORY_SCOPE_AGENT) < target)
            __builtin_amdgcn_s_sleep(2);
        __threadfence();
    }
    __syncthreads();
}

// ---------------------------------------------------------------------------
// Preamble mega-kernel:
//  [0,128)    weight convert/transpose fp32 [K][256] -> bf16 [256][K]
//  [128,192)  prop_add  (+ blk 128: zero d_out and barrier counter)
//  [192,449)  Wfold = W3@W_out -> bf16 WfT[16][256] + bfv
//  [449,577)  ETe[e][c] = eattr_e @ Wm_e + b_msg   (edge order)
// ---------------------------------------------------------------------------
__global__ __launch_bounds__(256) void k_pre(
    const float* __restrict__ W_in, const float* __restrict__ W_msg,
    const float* __restrict__ W_upd, const float* __restrict__ W_add,
    const float* __restrict__ W1, const float* __restrict__ W2,
    const float* __restrict__ W3, const float* __restrict__ b3,
    const float* __restrict__ W_out, const float* __restrict__ b_out,
    const float* __restrict__ props, const float* __restrict__ W_prop,
    const float* __restrict__ b_prop, const float* __restrict__ b_add,
    const float* __restrict__ b_msg, const float* __restrict__ eattr,
    unsigned short* __restrict__ wbf, unsigned short* __restrict__ WfT,
    float* __restrict__ bfv, float* __restrict__ prop_add,
    unsigned short* __restrict__ ETe, float* __restrict__ dout,
    int* __restrict__ barcnt)
{
    __shared__ __align__(16) char smem[16704];
    const int blk = blockIdx.x;
    const int tid = threadIdx.x;

    if (blk < 128) {                          // ---- weight convert/transpose
        float (*s)[65] = (float(*)[65])smem;
        const int wsel = blk >> 4;
        const int sub = blk & 15;
        const float* src; unsigned short* dst; int K = 256;
        switch (wsel) {
            case 0: src = W_in;              dst = wbf;                         K = 192; break;
            case 1: src = W_msg;             dst = wbf + 49152;                 break;
            case 2: src = W_upd;             dst = wbf + 49152 + 65536;         break;
            case 3: src = W_upd + 256 * 256; dst = wbf + 49152 + 2 * 65536;     break;
            case 4: src = W_add;             dst = wbf + 49152 + 3 * 65536;     break;
            case 5: src = W1;                dst = wbf + 49152 + 4 * 65536;     break;
            case 6: src = W1 + 256 * 256;    dst = wbf + 49152 + 5 * 65536;     break;
            default: src = W2;               dst = wbf + 49152 + 6 * 65536;     break;
        }
        const int k0 = (sub >> 2) * 64;
        const int n0 = (sub & 3) * 64;
        if (k0 >= K) return;
        const int tn = tid & 63;
        const int tg = tid >> 6;
        #pragma unroll
        for (int i = 0; i < 16; ++i) {
            const int kk = tg * 16 + i;
            s[kk][tn] = src[(size_t)(k0 + kk) * 256 + n0 + tn];
        }
        __syncthreads();
        #pragma unroll
        for (int i = 0; i < 16; ++i) {
            const int nn = tg * 16 + i;
            dst[(size_t)(n0 + nn) * K + k0 + tn] = f2bf(s[tn][nn]);
        }
    } else if (blk < 192) {                   // ---- prop_add (+ init)
        const int b = blk - 128;
        if (b == 0 && tid == 0) { *dout = 0.f; *barcnt = 0; }
        const float pv = props[b];
        float acc = b_add[tid];
        #pragma unroll 8
        for (int p = 0; p < PD; ++p) {
            const float e = fmaf(pv, W_prop[p], b_prop[p]);
            acc = fmaf(e, W_add[(256 + p) * 256 + tid], acc);
        }
        prop_add[b * 256 + tid] = acc;
    } else if (blk < 449) {                   // ---- Wfold + bfv
        float* part = (float*)smem;           // [4][NET]
        const int cb = blk - 192;             // 0..256
        float acc[NET] = {0.f, 0.f, 0.f, 0.f, 0.f};
        #pragma unroll
        for (int rep = 0; rep < 2; ++rep) {
            const int j = rep * 256 + tid;
            const float wv = (cb < 256) ? W3[(size_t)cb * 512 + j] : b3[j];
            #pragma unroll
            for (int t = 0; t < NET; ++t) acc[t] = fmaf(wv, W_out[j * NET + t], acc[t]);
        }
        #pragma unroll
        for (int t = 0; t < NET; ++t)
            for (int off = 32; off >= 1; off >>= 1) acc[t] += __shfl_down(acc[t], off);
        if ((tid & 63) == 0) {
            #pragma unroll
            for (int t = 0; t < NET; ++t) part[(tid >> 6) * NET + t] = acc[t];
        }
        __syncthreads();
        if (tid == 0) {
            float s[NET];
            #pragma unroll
            for (int t = 0; t < NET; ++t)
                s[t] = part[t] + part[NET + t] + part[2 * NET + t] + part[3 * NET + t];
            if (cb < 256) {
                #pragma unroll
                for (int t = 0; t < NET; ++t) WfT[t * 256 + cb] = f2bf(s[t]);
                #pragma unroll
                for (int t = NET; t < 16; ++t) WfT[t * 256 + cb] = 0;
            } else {
                #pragma unroll
                for (int t = 0; t < NET; ++t) bfv[t] = s[t] + b_out[t];
            }
        }
    } else {                                  // ---- edge term ETe (edge order)
        float* ea = (float*)smem;             // [128*5]
        const int eb = (blk - 449) * 128;
        if (tid < 160)
            *(float4*)&ea[tid * 4] = *(const float4*)(eattr + (size_t)eb * 5 + tid * 4);
        __syncthreads();
        const float* Wme = W_msg + 256 * 256;
        const float w0 = Wme[0 * 256 + tid];
        const float w1 = Wme[1 * 256 + tid];
        const float w2 = Wme[2 * 256 + tid];
        const float w3 = Wme[3 * 256 + tid];
        const float w4 = Wme[4 * 256 + tid];
        const float bm = b_msg[tid];
        for (int i = 0; i < 128; ++i) {
            const float* a = ea + i * 5;
            float v = bm;
            v = fmaf(a[0], w0, v); v = fmaf(a[1], w1, v); v = fmaf(a[2], w2, v);
            v = fmaf(a[3], w3, v); v = fmaf(a[4], w4, v);
            ETe[(size_t)(eb + i) * 256 + tid] = f2bf(v);
        }
    }
}

// ---------------------------------------------------------------------------
// Single-block CSR build: LDS hist -> scan -> scatter of (src,eid) recs.
// ---------------------------------------------------------------------------
__global__ __launch_bounds__(1024) void csr_all(const int* __restrict__ eidx,
                                                int* __restrict__ row_start,
                                                int2* __restrict__ recs)
{
    __shared__ int sdeg[4096];
    __shared__ int scan1[1024];
    const int tid = threadIdx.x;
    #pragma unroll
    for (int i = 0; i < 4; ++i) sdeg[tid * 4 + i] = 0;
    __syncthreads();
    #pragma unroll
    for (int r = 0; r < NE / 1024; ++r)
        atomicAdd(&sdeg[eidx[NE + r * 1024 + tid]], 1);
    __syncthreads();
    const int l0 = sdeg[tid * 4 + 0];
    const int l1 = sdeg[tid * 4 + 1];
    const int l2 = sdeg[tid * 4 + 2];
    const int l3 = sdeg[tid * 4 + 3];
    scan1[tid] = l0 + l1 + l2 + l3;
    __syncthreads();
    for (int off = 1; off < 1024; off <<= 1) {
        const int v = scan1[tid];
        const int add = (tid >= off) ? scan1[tid - off] : 0;
        __syncthreads();
        scan1[tid] = v + add;
        __syncthreads();
    }
    const int base = (tid == 0) ? 0 : scan1[tid - 1];
    row_start[tid * 4 + 0] = base;
    row_start[tid * 4 + 1] = base + l0;
    row_start[tid * 4 + 2] = base + l0 + l1;
    row_start[tid * 4 + 3] = base + l0 + l1 + l2;
    sdeg[tid * 4 + 0] = base;
    sdeg[tid * 4 + 1] = base + l0;
    sdeg[tid * 4 + 2] = base + l0 + l1;
    sdeg[tid * 4 + 3] = base + l0 + l1 + l2;
    if (tid == 0) row_start[4096] = NE;
    __syncthreads();
    #pragma unroll
    for (int r = 0; r < NE / 1024; ++r) {
        const int e = r * 1024 + tid;
        const int d = eidx[NE + e];
        const int s = eidx[e];
        const int pos = atomicAdd(&sdeg[d], 1);
        int2 rec; rec.x = s; rec.y = e;
        recs[pos] = rec;
    }
}

// ---------------------------------------------------------------------------
// Mega node kernel: all 5 rounds in ONE launch, grid 256 x 1024 (1 block/CU),
// custom grid barriers between rounds. h lives in LDS the whole time.
// ---------------------------------------------------------------------------
__global__ __launch_bounds__(1024) void mega(
    const float* __restrict__ x, const unsigned short* __restrict__ ETe,
    const int* __restrict__ row_start, const int2* __restrict__ recs,
    const unsigned short* __restrict__ W_inT, const unsigned short* __restrict__ WmT,
    const unsigned short* __restrict__ WuaT, const unsigned short* __restrict__ WubT,
    const unsigned short* __restrict__ W_addT, const unsigned short* __restrict__ W1aT,
    const unsigned short* __restrict__ W1bT,
    const float* __restrict__ b_in, const float* __restrict__ b_upd,
    const float* __restrict__ prop_add,
    unsigned short* __restrict__ P0g, unsigned short* __restrict__ P1g,
    unsigned short* __restrict__ A2g, int* __restrict__ barcnt)
{
    __shared__ __align__(16) unsigned short Ha[16 * FSTR];
    __shared__ __align__(16) unsigned short Hb[16 * FSTR];
    __shared__ __align__(16) unsigned short Ag[16 * FSTR];
    __shared__ __align__(16) unsigned short H2s[16 * FSTR];
    const int tid = threadIdx.x;
    const int w = tid >> 6;
    const int lane = tid & 63;
    const int q = lane >> 4;
    const int tx = lane & 15;
    const int m0 = blockIdx.x * 16;
    const int col = w * 16 + tx;

    // ---- round 0: h0 = relu(x@W_in + b_in) -> Ha;  P0 = h0@Wm
    {
        f32x4 acc = (f32x4)0.f;
        #pragma unroll
        for (int s = 0; s < 6; ++s) {
            const int k0 = s * 32;
            const float* ap = x + (size_t)(m0 + tx) * 192 + k0 + q * 8;
            const float4 v0 = *(const float4*)ap;
            const float4 v1 = *(const float4*)(ap + 4);
            short8 af;
            af[0] = (short)f2bf(v0.x); af[1] = (short)f2bf(v0.y);
            af[2] = (short)f2bf(v0.z); af[3] = (short)f2bf(v0.w);
            af[4] = (short)f2bf(v1.x); af[5] = (short)f2bf(v1.y);
            af[6] = (short)f2bf(v1.z); af[7] = (short)f2bf(v1.w);
            const short8 bfr = *(const short8*)(W_inT + (size_t)col * 192 + k0 + q * 8);
            acc = __builtin_amdgcn_mfma_f32_16x16x32_bf16(af, bfr, acc, 0, 0, 0);
        }
        const float bv = b_in[col];
        #pragma unroll
        for (int r = 0; r < 4; ++r)
            Ha[(q * 4 + r) * FSTR + col] = f2bf(fmaxf(acc[r] + bv, 0.f));
        __syncthreads();
        acc = (f32x4)0.f;
        #pragma unroll
        for (int s = 0; s < 8; ++s) {
            const int k0 = s * 32;
            const short8 af = *(const short8*)&Ha[tx * FSTR + k0 + q * 8];
            const short8 bfr = *(const short8*)(WmT + (size_t)col * 256 + k0 + q * 8);
            acc = __builtin_amdgcn_mfma_f32_16x16x32_bf16(af, bfr, acc, 0, 0, 0);
        }
        #pragma unroll
        for (int r = 0; r < 4; ++r)
            P0g[(size_t)(m0 + q * 4 + r) * 256 + col] = f2bf(acc[r]);
    }
    grid_barrier(barcnt, 256);

    unsigned short* Pr = P0g;
    unsigned short* Pw = P1g;
    unsigned short* cur = Ha;
    unsigned short* nxt = Hb;

    for (int round = 1; round <= 4; ++round) {
        // ---- agg: wave w <-> node m0+w; unroll-2 pipelined CSR gather
        {
            const int node = m0 + w;
            const int beg = row_start[node];
            const int end = row_start[node + 1];
            const int c = lane * 4;
            float a0 = 0.f, a1 = 0.f, a2 = 0.f, a3 = 0.f;
            int idx = beg;
            for (; idx + 2 <= end; idx += 2) {
                const int2 r0 = recs[idx];
                const int2 r1 = recs[idx + 1];
                const uint2 p0 = *(const uint2*)(Pr + (size_t)r0.x * 256 + c);
                const uint2 e0 = *(const uint2*)(ETe + (size_t)r0.y * 256 + c);
                const uint2 p1 = *(const uint2*)(Pr + (size_t)r1.x * 256 + c);
                const uint2 e1 = *(const uint2*)(ETe + (size_t)r1.y * 256 + c);
                a0 += fmaxf(bf_lo(p0.x) + bf_lo(e0.x), 0.f) + fmaxf(bf_lo(p1.x) + bf_lo(e1.x), 0.f);
                a1 += fmaxf(bf_hi(p0.x) + bf_hi(e0.x), 0.f) + fmaxf(bf_hi(p1.x) + bf_hi(e1.x), 0.f);
                a2 += fmaxf(bf_lo(p0.y) + bf_lo(e0.y), 0.f) + fmaxf(bf_lo(p1.y) + bf_lo(e1.y), 0.f);
                a3 += fmaxf(bf_hi(p0.y) + bf_hi(e0.y), 0.f) + fmaxf(bf_hi(p1.y) + bf_hi(e1.y), 0.f);
            }
            if (idx < end) {
                const int2 r0 = recs[idx];
                const uint2 p0 = *(const uint2*)(Pr + (size_t)r0.x * 256 + c);
                const uint2 e0 = *(const uint2*)(ETe + (size_t)r0.y * 256 + c);
                a0 += fmaxf(bf_lo(p0.x) + bf_lo(e0.x), 0.f);
                a1 += fmaxf(bf_hi(p0.x) + bf_hi(e0.x), 0.f);
                a2 += fmaxf(bf_lo(p0.y) + bf_lo(e0.y), 0.f);
                a3 += fmaxf(bf_hi(p0.y) + bf_hi(e0.y), 0.f);
            }
            uint2 o; o.x = pack2(a0, a1); o.y = pack2(a2, a3);
            *(uint2*)&Ag[w * FSTR + c] = o;
        }
        __syncthreads();

        // ---- act = relu(cur@Wua + Ag@Wub + b_upd) -> nxt
        {
            f32x4 acc = (f32x4)0.f;
            #pragma unroll
            for (int s = 0; s < 8; ++s) {
                const int k0 = s * 32;
                const short8 af = *(const short8*)&cur[tx * FSTR + k0 + q * 8];
                const short8 bfr = *(const short8*)(WuaT + (size_t)col * 256 + k0 + q * 8);
                acc = __builtin_amdgcn_mfma_f32_16x16x32_bf16(af, bfr, acc, 0, 0, 0);
            }
            #pragma unroll
            for (int s = 0; s < 8; ++s) {
                const int k0 = s * 32;
                const short8 af = *(const short8*)&Ag[tx * FSTR + k0 + q * 8];
                const short8 bfr = *(const short8*)(WubT + (size_t)col * 256 + k0 + q * 8);
                acc = __builtin_amdgcn_mfma_f32_16x16x32_bf16(af, bfr, acc, 0, 0, 0);
            }
            const float bv = b_upd[col];
            #pragma unroll
            for (int r = 0; r < 4; ++r)
                nxt[(q * 4 + r) * FSTR + col] = f2bf(fmaxf(acc[r] + bv, 0.f));
        }
        __syncthreads();

        if (round < 4) {
            // ---- P = act@Wm -> Pw
            f32x4 acc = (f32x4)0.f;
            #pragma unroll
            for (int s = 0; s < 8; ++s) {
                const int k0 = s * 32;
                const short8 af = *(const short8*)&nxt[tx * FSTR + k0 + q * 8];
                const short8 bfr = *(const short8*)(WmT + (size_t)col * 256 + k0 + q * 8);
                acc = __builtin_amdgcn_mfma_f32_16x16x32_bf16(af, bfr, acc, 0, 0, 0);
            }
            #pragma unroll
            for (int r = 0; r < 4; ++r)
                Pw[(size_t)(m0 + q * 4 + r) * 256 + col] = f2bf(acc[r]);
            grid_barrier(barcnt, 256 * (round + 1));
            unsigned short* t1 = Pr; Pr = Pw; Pw = t1;
            unsigned short* t2 = cur; cur = nxt; nxt = t2;
        } else {
            // ---- final: embg = act@W_add + prop_add -> H2s; A1=embg@W1a; A2=embg@W1b
            f32x4 acc = (f32x4)0.f;
            #pragma unroll
            for (int s = 0; s < 8; ++s) {
                const int k0 = s * 32;
                const short8 af = *(const short8*)&nxt[tx * FSTR + k0 + q * 8];
                const short8 bfr = *(const short8*)(W_addT + (size_t)col * 256 + k0 + q * 8);
                acc = __builtin_amdgcn_mfma_f32_16x16x32_bf16(af, bfr, acc, 0, 0, 0);
            }
            const float pv = prop_add[(m0 >> 6) * 256 + col];
            #pragma unroll
            for (int r = 0; r < 4; ++r)
                H2s[(q * 4 + r) * FSTR + col] = f2bf(acc[r] + pv);
            __syncthreads();
            for (int which = 0; which < 2; ++which) {
                const unsigned short* WT = which ? W1bT : W1aT;
                unsigned short* op = which ? A2g : P0g;   // A1 -> P0 (free), A2 -> A2g
                acc = (f32x4)0.f;
                #pragma unroll
                for (int s = 0; s < 8; ++s) {
                    const int k0 = s * 32;
                    const short8 af = *(const short8*)&H2s[tx * FSTR + k0 + q * 8];
                    const short8 bfr = *(const short8*)(WT + (size_t)col * 256 + k0 + q * 8);
                    acc = __builtin_amdgcn_mfma_f32_16x16x32_bf16(af, bfr, acc, 0, 0, 0);
                }
                #pragma unroll
                for (int r = 0; r < 4; ++r)
                    op[(size_t)(m0 + q * 4 + r) * 256 + col] = f2bf(acc[r]);
            }
        }
    }
}

// ---------------------------------------------------------------------------
// Fused pair MLP + CE (round-8 validated). Grid 256 x 512; 4 tiles of 64
// pairs per block; W2 fragments preloaded once into 32 short8 registers.
// ---------------------------------------------------------------------------
__global__ __launch_bounds__(512, 1) void pair_k(
    const unsigned short* __restrict__ A1t, const unsigned short* __restrict__ A2t,
    const float* __restrict__ b1, const unsigned short* __restrict__ W2T,
    const float* __restrict__ b2, const unsigned short* __restrict__ WfT,
    const float* __restrict__ bfv,
    const int* __restrict__ sel_b, const int* __restrict__ sel_i,
    const int* __restrict__ sel_j, const int* __restrict__ golden,
    float* __restrict__ out)
{
    __shared__ __align__(16) unsigned short sbuf[64 * H1STR];
    __shared__ __align__(16) unsigned short b1s[256];
    __shared__ float Lg[64 * 8];
    __shared__ int sidx[64 * PTILES], didx[64 * PTILES], gold[64 * PTILES];

    const int tid = threadIdx.x;
    const int w = tid >> 6;
    const int lane = tid & 63;
    const int q = lane >> 4;
    const int tx = lane & 15;
    const int m = lane & 31;
    const int hh = lane >> 5;
    const int e0 = blockIdx.x * 64 * PTILES;

    if (tid < 64 * PTILES) {
        const int e = e0 + tid;
        const int b = sel_b[e];
        sidx[tid] = b * N_PER_B + sel_i[e];
        didx[tid] = b * N_PER_B + sel_j[e];
        gold[tid] = golden[e];
    }
    if (tid < 256) b1s[tid] = f2bf(b1[tid]);

    const int pt = w & 1;
    const int cg = w >> 1;
    short8 Breg[32];
    {
        const unsigned short* bb = W2T + (size_t)(cg * 64 + m) * 256 + hh * 8;
        #pragma unroll
        for (int cc = 0; cc < 2; ++cc)
            #pragma unroll
            for (int s = 0; s < 16; ++s)
                Breg[cc * 16 + s] = *(const short8*)(bb + (size_t)cc * 32 * 256 + s * 16);
    }
    __syncthreads();

    float total = 0.f;

    for (int t = 0; t < PTILES; ++t) {
        {
            const int hw = tid >> 5;
            #pragma unroll
            for (int j = 0; j < 4; ++j) {
                const int p = j * 16 + hw;
                const unsigned short* r1 = A1t + (size_t)sidx[t * 64 + p] * 256 + m * 8;
                const unsigned short* r2 = A2t + (size_t)didx[t * 64 + p] * 256 + m * 8;
                const uint4 u1 = *(const uint4*)r1;
                const uint4 u2 = *(const uint4*)r2;
                const uint4 ub = *(const uint4*)(b1s + m * 8);
                uint2 lo2, hi2;
                lo2.x = addrelu2(u1.x, u2.x, ub.x);
                lo2.y = addrelu2(u1.y, u2.y, ub.y);
                hi2.x = addrelu2(u1.z, u2.z, ub.z);
                hi2.y = addrelu2(u1.w, u2.w, ub.w);
                unsigned short* dbase = sbuf + p * H1STR + m * 8;
                *(uint2*)(dbase) = lo2;
                *(uint2*)(dbase + 4) = hi2;
            }
        }
        __syncthreads();

        f32x16 acc0 = (f32x16)0.f;
        f32x16 acc1 = (f32x16)0.f;
        {
            const unsigned short* arow = sbuf + (size_t)(pt * 32 + m) * H1STR + hh * 8;
            #pragma unroll
            for (int s = 0; s < 16; ++s) {
                const short8 af = ld_frag(arow + s * 16);
                acc0 = __builtin_amdgcn_mfma_f32_32x32x16_bf16(af, Breg[s], acc0, 0, 0, 0);
                acc1 = __builtin_amdgcn_mfma_f32_32x32x16_bf16(af, Breg[16 + s], acc1, 0, 0, 0);
            }
        }
        __syncthreads();

        #pragma unroll
        for (int cc = 0; cc < 2; ++cc) {
            const f32x16* ap = cc ? &acc1 : &acc0;
            const int col = cg * 64 + cc * 32 + m;
            const float bv = b2[col];
            #pragma unroll
            for (int reg = 0; reg < 16; ++reg) {
                const int prow = pt * 32 + (reg & 3) + 8 * (reg >> 2) + 4 * hh;
                sbuf[prow * H1STR + col] = f2bf(fmaxf((*ap)[reg] + bv, 0.f));
            }
        }
        __syncthreads();

        if (w < 4) {
            f32x4 accL = (f32x4)0.f;
            const unsigned short* a2row = sbuf + (size_t)(w * 16 + tx) * H1STR + q * 8;
            const unsigned short* bWf = WfT + (size_t)tx * 256 + q * 8;
            #pragma unroll
            for (int s = 0; s < 8; ++s) {
                const short8 af = ld_frag(a2row + s * 32);
                const short8 bfr = *(const short8*)(bWf + s * 32);
                accL = __builtin_amdgcn_mfma_f32_16x16x32_bf16(af, bfr, accL, 0, 0, 0);
            }
            if (tx < NET) {
                const float bb = bfv[tx];
                #pragma unroll
                for (int reg = 0; reg < 4; ++reg)
                    Lg[(w * 16 + q * 4 + reg) * 8 + tx] = accL[reg] + bb;
            }
        }
        __syncthreads();

        if (tid < 64) {
            float lg[NET];
            #pragma unroll
            for (int tt = 0; tt < NET; ++tt) lg[tt] = Lg[tid * 8 + tt];
            float mx = lg[0];
            #pragma unroll
            for (int tt = 1; tt < NET; ++tt) mx = fmaxf(mx, lg[tt]);
            float s = 0.f;
            #pragma unroll
            for (int tt = 0; tt < NET; ++tt) s += expf(lg[tt] - mx);
            float ls = mx + logf(s) - lg[gold[t * 64 + tid]];
            #pragma unroll
            for (int off = 32; off >= 1; off >>= 1) ls += __shfl_xor(ls, off);
            total += ls;
        }
        __syncthreads();
    }

    if (tid == 0) atomicAdd(out, total * (1.0f / NSEL));
}

// ---------------------------------------------------------------------------
extern "C" void kernel_launch(void* const* d_in, const int* in_sizes, int n_in,
                              void* d_out, int out_size, void* d_ws, size_t ws_size,
                              hipStream_t stream) {
    (void)in_sizes; (void)n_in; (void)out_size; (void)ws_size;
    const float* x      = (const float*)d_in[0];
    const int*   eidx   = (const int*)d_in[1];
    const float* eattr  = (const float*)d_in[2];
    const float* props  = (const float*)d_in[3];
    const int*   sel_b  = (const int*)d_in[4];
    const int*   sel_i  = (const int*)d_in[5];
    const int*   sel_j  = (const int*)d_in[6];
    const int*   golden = (const int*)d_in[7];
    const float* W_prop = (const float*)d_in[8];
    const float* b_prop = (const float*)d_in[9];
    const float* W_in   = (const float*)d_in[10];
    const float* b_in   = (const float*)d_in[11];
    const float* W_msg  = (const float*)d_in[12];
    const float* b_msg  = (const float*)d_in[13];
    const float* W_upd  = (const float*)d_in[14];
    const float* b_upd  = (const float*)d_in[15];
    const float* W_add  = (const float*)d_in[16];
    const float* b_add  = (const float*)d_in[17];
    const float* W1     = (const float*)d_in[18];
    const float* b1     = (const float*)d_in[19];
    const float* W2     = (const float*)d_in[20];
    const float* b2     = (const float*)d_in[21];
    const float* W3     = (const float*)d_in[22];
    const float* b3     = (const float*)d_in[23];
    const float* W_out  = (const float*)d_in[24];
    const float* b_out  = (const float*)d_in[25];

    const size_t SEG = (size_t)BN * 256;
    unsigned short* P0   = (unsigned short*)d_ws;   // P even; final A1
    unsigned short* P1   = P0 + SEG;
    unsigned short* A2b  = P1 + SEG;
    unsigned short* ETe  = A2b + SEG;               // [NE][256] edge order
    unsigned short* wbf  = ETe + (size_t)NE * 256;
    unsigned short* W_inT  = wbf;                   // [256][192]
    unsigned short* WmT    = wbf + 49152;
    unsigned short* WuaT   = WmT + 65536;
    unsigned short* WubT   = WuaT + 65536;
    unsigned short* W_addT = WubT + 65536;
    unsigned short* W1aT   = W_addT + 65536;
    unsigned short* W1bT   = W1aT + 65536;
    unsigned short* W2T    = W1bT + 65536;
    unsigned short* WfT    = W2T + 65536;           // [16][256]
    float* prop_add = (float*)(WfT + 4096);         // [64][256]
    float* bfv = prop_add + 64 * 256;               // [16]
    int* barcnt    = (int*)(bfv + 16);
    int* row_start = barcnt + 16;                   // [4097]
    int2* recs     = (int2*)(row_start + 4104);     // [NE]

    k_pre<<<577, 256, 0, stream>>>(W_in, W_msg, W_upd, W_add, W1, W2, W3, b3,
                                   W_out, b_out, props, W_prop, b_prop, b_add,
                                   b_msg, eattr, wbf, WfT, bfv, prop_add, ETe,
                                   (float*)d_out, barcnt);
    csr_all<<<1, 1024, 0, stream>>>(eidx, row_start, recs);
    mega<<<256, 1024, 0, stream>>>(x, ETe, row_start, recs,
                                   W_inT, WmT, WuaT, WubT, W_addT, W1aT, W1bT,
                                   b_in, b_upd, prop_add, P0, P1, A2b, barcnt);
    pair_k<<<256, 512, 0, stream>>>(P0, A2b, b1, W2T, b2, WfT, bfv,
                                    sel_b, sel_i, sel_j, golden, (float*)d_out);
}